// Round 2
// baseline (1622.231 us; speedup 1.0000x reference)
//
#include <hip/hip_runtime.h>
#include <hip/hip_bf16.h>

typedef __hip_bfloat16 bf16;

__device__ __forceinline__ float b2f(bf16 x) { return __bfloat162float(x); }
__device__ __forceinline__ float2 bfpair(unsigned int u) {
  union { unsigned int i; float f; } a, b;
  a.i = u << 16; b.i = u & 0xffff0000u;
  float2 r; r.x = a.f; r.y = b.f; return r;
}

// ---------------- encoder: h = relu(LN(x @ enc_w + enc_b)) ----------------
// grid 16384 (one row), 256 threads (one out col each)
__global__ __launch_bounds__(256) void k_enc(
    const float* __restrict__ x, const float* __restrict__ w,
    const float* __restrict__ bia, const float* __restrict__ g,
    const float* __restrict__ beta, float* __restrict__ h) {
  __shared__ float xs[512];
  __shared__ float red[18];
  const int tid = threadIdx.x;
  const int row = blockIdx.x;
  const float2 u = ((const float2*)(x + (size_t)row * 512))[tid];
  xs[2 * tid] = u.x;
  xs[2 * tid + 1] = u.y;
  __syncthreads();
  const int col = tid;
  float acc = bia[col];
  const float* wc = w + col;
  for (int i = 0; i < 512; i += 8) {
    const float4 xa = *(const float4*)&xs[i];
    const float4 xb = *(const float4*)&xs[i + 4];
    acc += xa.x * wc[(i + 0) * 256] + xa.y * wc[(i + 1) * 256] +
           xa.z * wc[(i + 2) * 256] + xa.w * wc[(i + 3) * 256] +
           xb.x * wc[(i + 4) * 256] + xb.y * wc[(i + 5) * 256] +
           xb.z * wc[(i + 6) * 256] + xb.w * wc[(i + 7) * 256];
  }
  float s1 = acc, s2 = acc * acc;
#pragma unroll
  for (int o = 32; o > 0; o >>= 1) { s1 += __shfl_down(s1, o); s2 += __shfl_down(s2, o); }
  const int wv = tid >> 6;
  if ((tid & 63) == 0) { red[wv] = s1; red[8 + wv] = s2; }
  __syncthreads();
  if (tid == 0) {
    red[16] = red[0] + red[1] + red[2] + red[3];
    red[17] = red[8] + red[9] + red[10] + red[11];
  }
  __syncthreads();
  const float mu = red[16] * (1.f / 256.f);
  const float var = red[17] * (1.f / 256.f) - mu * mu;
  const float rstd = rsqrtf(var + 1e-5f);
  const float hv = (acc - mu) * rstd * g[col] + beta[col];
  h[(size_t)row * 256 + col] = fmaxf(hv, 0.f);
}

// ---------------- qkv: q,k,v = h@W + b ; k stored transposed ----------------
// grid 16384, 256 threads
__global__ __launch_bounds__(256) void k_qkv(
    const float* __restrict__ h, const float* __restrict__ wq, const float* __restrict__ bq,
    const float* __restrict__ wk, const float* __restrict__ bk,
    const float* __restrict__ wvp, const float* __restrict__ bv,
    float* __restrict__ q, float* __restrict__ kT, float* __restrict__ v) {
  __shared__ float hs[256];
  const int tid = threadIdx.x;
  const int row = blockIdx.x;
  const int b = row >> 11, n = row & 2047;
  hs[tid] = h[(size_t)row * 256 + tid];
  __syncthreads();
  float aq = bq[tid], ak = bk[tid], av = bv[tid];
  for (int i = 0; i < 256; i += 4) {
    const float4 hv = *(const float4*)&hs[i];
    const int o0 = i * 256 + tid;
    aq += hv.x * wq[o0] + hv.y * wq[o0 + 256] + hv.z * wq[o0 + 512] + hv.w * wq[o0 + 768];
    ak += hv.x * wk[o0] + hv.y * wk[o0 + 256] + hv.z * wk[o0 + 512] + hv.w * wk[o0 + 768];
    av += hv.x * wvp[o0] + hv.y * wvp[o0 + 256] + hv.z * wvp[o0 + 512] + hv.w * wvp[o0 + 768];
  }
  q[(size_t)row * 256 + tid] = aq;
  v[(size_t)row * 256 + tid] = av;
  kT[((size_t)b * 256 + tid) * 2048 + n] = ak;
}

// ---------------- attention: agg = (softmax(qk^T/16)*adj*colmask) @ v -------
// grid (256 tiles, 8 batches), 256 threads; TQ=8 query rows per block
__global__ __launch_bounds__(256) void k_attn(
    const float* __restrict__ q, const float* __restrict__ kT, const float* __restrict__ v,
    const float* __restrict__ coords, const int* __restrict__ mask,
    const float* __restrict__ gam, float* __restrict__ agg) {
  __shared__ float qs[256][8];                       // qs[i][qq], 8 KB
  __shared__ __align__(16) bf16 sc[2048][8];         // scores/weights, 32 KB
  __shared__ float qx[8], qy[8], mxl[16];
  const int t = threadIdx.x;
  const int b = blockIdx.y;
  const int n0 = blockIdx.x * 8;
  const size_t base = (size_t)b * 2048;
#pragma unroll
  for (int qq = 0; qq < 8; ++qq)
    qs[t][qq] = q[(base + n0 + qq) * 256 + t];
  if (t < 8) {
    const float2 c = ((const float2*)coords)[base + n0 + t];
    qx[t] = c.x; qy[t] = c.y;
  }
  const float ag = fabsf(gam[0]);
  float xm[8], ym[8], mf[8];
#pragma unroll
  for (int j = 0; j < 8; ++j) {
    const int m = t + 256 * j;
    const float2 c = ((const float2*)coords)[base + m];
    xm[j] = c.x; ym[j] = c.y;
    mf[j] = mask[base + m] ? 0.f : 1.f;
  }
  __syncthreads();
  // phase 1: raw scores for 8 q's x 8 m's per thread
  float acc[8][8];
#pragma unroll
  for (int qq = 0; qq < 8; ++qq)
#pragma unroll
    for (int j = 0; j < 8; ++j) acc[qq][j] = 0.f;
  const float* kTb = kT + (size_t)b * 256 * 2048;
  for (int i = 0; i < 256; ++i) {
    float kv[8];
#pragma unroll
    for (int j = 0; j < 8; ++j) kv[j] = kTb[(size_t)i * 2048 + t + 256 * j];
    const float4 qa = *(const float4*)&qs[i][0];
    const float4 qb = *(const float4*)&qs[i][4];
#pragma unroll
    for (int j = 0; j < 8; ++j) {
      acc[0][j] += qa.x * kv[j]; acc[1][j] += qa.y * kv[j];
      acc[2][j] += qa.z * kv[j]; acc[3][j] += qa.w * kv[j];
      acc[4][j] += qb.x * kv[j]; acc[5][j] += qb.y * kv[j];
      acc[6][j] += qb.z * kv[j]; acc[7][j] += qb.w * kv[j];
    }
  }
  const float inv16 = 0.0625f;  // 1/sqrt(D)
#pragma unroll
  for (int j = 0; j < 8; ++j)
#pragma unroll
    for (int qq = 0; qq < 8; ++qq)
      sc[t + 256 * j][qq] = __float2bfloat16(acc[qq][j] * inv16);
  __syncthreads();
  // softmax stats: 32 threads per q, exact max + full-row sum (mask NOT applied here)
  {
    const int qq = t >> 5, l = t & 31;
    float mx = -1e30f;
    for (int j2 = 0; j2 < 64; ++j2) mx = fmaxf(mx, b2f(sc[l + 32 * j2][qq]));
#pragma unroll
    for (int o = 16; o > 0; o >>= 1) mx = fmaxf(mx, __shfl_xor(mx, o));
    if (l == 0) mxl[qq] = mx;
    __syncthreads();
    const float mxq = mxl[qq];
    float s = 0.f;
    for (int j2 = 0; j2 < 64; ++j2) s += __expf(b2f(sc[l + 32 * j2][qq]) - mxq);
#pragma unroll
    for (int o = 16; o > 0; o >>= 1) s += __shfl_xor(s, o);
    if (l == 0) mxl[8 + qq] = 1.f / s;
    __syncthreads();
  }
  // write back final weights: softmax * spatial_adj * colmask
#pragma unroll
  for (int qq = 0; qq < 8; ++qq) {
    const float xn = qx[qq], yn = qy[qq];
    const float sqn = xn * xn + yn * yn;
    const float mxq = mxl[qq], rl = mxl[8 + qq];
#pragma unroll
    for (int j = 0; j < 8; ++j) {
      const float d2 = sqn + xm[j] * xm[j] + ym[j] * ym[j] - 2.f * (xn * xm[j] + yn * ym[j]);
      const float dist = sqrtf(fmaxf(d2, 0.f));
      const float adj = __expf(-dist * ag);
      const float sq16 = b2f(__float2bfloat16(acc[qq][j] * inv16));  // match stored quantization
      const float wgt = __expf(sq16 - mxq) * rl * adj * mf[j];
      sc[t + 256 * j][qq] = __float2bfloat16(wgt);
    }
  }
  __syncthreads();
  // phase 2: O[qq][d=t] = sum_m w * v[m][d]
  float o[8];
#pragma unroll
  for (int qq = 0; qq < 8; ++qq) o[qq] = 0.f;
  const float* vb = v + (size_t)b * 2048 * 256;
#pragma unroll 4
  for (int m = 0; m < 2048; ++m) {
    const float vv = vb[(size_t)m * 256 + t];
    const uint4 wr = *(const uint4*)&sc[m][0];
    const float2 w01 = bfpair(wr.x), w23 = bfpair(wr.y), w45 = bfpair(wr.z), w67 = bfpair(wr.w);
    o[0] += w01.x * vv; o[1] += w01.y * vv; o[2] += w23.x * vv; o[3] += w23.y * vv;
    o[4] += w45.x * vv; o[5] += w45.y * vv; o[6] += w67.x * vv; o[7] += w67.y * vv;
  }
#pragma unroll
  for (int qq = 0; qq < 8; ++qq)
    agg[(base + n0 + qq) * 256 + t] = o[qq];
}

// ---------------- bn: out = relu(LN(agg @ bn_w + bn_b)) ----------------
// grid 16384, 128 threads
__global__ __launch_bounds__(128) void k_bn(
    const float* __restrict__ agg, const float* __restrict__ w, const float* __restrict__ bia,
    const float* __restrict__ g, const float* __restrict__ beta, float* __restrict__ out) {
  __shared__ float as_[256];
  __shared__ float red[8];
  const int tid = threadIdx.x;
  const int row = blockIdx.x;
  as_[tid] = agg[(size_t)row * 256 + tid];
  as_[128 + tid] = agg[(size_t)row * 256 + 128 + tid];
  __syncthreads();
  float acc = bia[tid];
  for (int i = 0; i < 256; i += 4) {
    const float4 a4 = *(const float4*)&as_[i];
    const int o0 = i * 128 + tid;
    acc += a4.x * w[o0] + a4.y * w[o0 + 128] + a4.z * w[o0 + 256] + a4.w * w[o0 + 384];
  }
  float s1 = acc, s2 = acc * acc;
#pragma unroll
  for (int o = 32; o > 0; o >>= 1) { s1 += __shfl_down(s1, o); s2 += __shfl_down(s2, o); }
  if ((tid & 63) == 0) { red[tid >> 6] = s1; red[2 + (tid >> 6)] = s2; }
  __syncthreads();
  if (tid == 0) { red[4] = red[0] + red[1]; red[5] = red[2] + red[3]; }
  __syncthreads();
  const float mu = red[4] * (1.f / 128.f);
  const float var = red[5] * (1.f / 128.f) - mu * mu;
  const float rstd = rsqrtf(var + 1e-5f);
  const float ov = (acc - mu) * rstd * g[tid] + beta[tid];
  out[(size_t)row * 128 + tid] = fmaxf(ov, 0.f);
}

// ---------------- masked mean pool ----------------
// grid 8, 128 threads; writes pooled (fp32 ws) AND d_out[80..1104)
__global__ __launch_bounds__(128) void k_pool(
    const float* __restrict__ out_bn, const int* __restrict__ mask,
    float* __restrict__ pooled, float* __restrict__ dout) {
  const int b = blockIdx.x, d = threadIdx.x;
  float s = 0.f, cnt = 0.f;
  const float* ob = out_bn + (size_t)b * 2048 * 128;
  const int* mb = mask + b * 2048;
  for (int n = 0; n < 2048; ++n) {
    const float wgt = mb[n] ? 0.f : 1.f;
    s += wgt * ob[(size_t)n * 128 + d];
    cnt += wgt;
  }
  const float p = s / fmaxf(cnt, 1e-9f);
  pooled[b * 128 + d] = p;
  dout[80 + b * 128 + d] = p;
}

// ---------------- head: logits = relu(pooled@c1)@c2 ----------------
// grid 8, 64 threads
__global__ __launch_bounds__(64) void k_head(
    const float* __restrict__ pooled, const float* __restrict__ c1w, const float* __restrict__ c1b,
    const float* __restrict__ c2w, const float* __restrict__ c2b, float* __restrict__ dout) {
  __shared__ float ps[128];
  __shared__ float h1[64];
  const int b = blockIdx.x, t = threadIdx.x;
  ps[t] = pooled[b * 128 + t];
  ps[64 + t] = pooled[b * 128 + 64 + t];
  __syncthreads();
  float acc = c1b[t];
  for (int d = 0; d < 128; ++d) acc += ps[d] * c1w[d * 64 + t];
  h1[t] = fmaxf(acc, 0.f);
  __syncthreads();
  if (t < 10) {
    float a2 = c2b[t];
    for (int j = 0; j < 64; ++j) a2 += h1[j] * c2w[j * 10 + t];
    dout[b * 10 + t] = a2;
  }
}

extern "C" void kernel_launch(void* const* d_in, const int* in_sizes, int n_in,
                              void* d_out, int out_size, void* d_ws, size_t ws_size,
                              hipStream_t stream) {
  const float* lf     = (const float*)d_in[0];
  const float* coords = (const float*)d_in[1];
  const int*   mask   = (const int*)d_in[2];
  const float* enc_w  = (const float*)d_in[3];
  const float* enc_b  = (const float*)d_in[4];
  const float* enc_g  = (const float*)d_in[5];
  const float* enc_be = (const float*)d_in[6];
  const float* gamma  = (const float*)d_in[7];
  const float* wq     = (const float*)d_in[8];
  const float* bq     = (const float*)d_in[9];
  const float* wk     = (const float*)d_in[10];
  const float* bk     = (const float*)d_in[11];
  const float* wv     = (const float*)d_in[12];
  const float* bv     = (const float*)d_in[13];
  const float* bn_w   = (const float*)d_in[14];
  const float* bn_b   = (const float*)d_in[15];
  const float* bn_g   = (const float*)d_in[16];
  const float* bn_be  = (const float*)d_in[17];
  const float* c1w    = (const float*)d_in[18];
  const float* c1b    = (const float*)d_in[19];
  const float* c2w    = (const float*)d_in[20];
  const float* c2b    = (const float*)d_in[21];

  // workspace layout (floats), with aliasing of dead buffers:
  //   [0 .. 4M)      h      (16 MB)   -> later reused as agg
  //   [4M .. 8M)     q      (16 MB)   -> later reused as obn (8 MB used)
  //   [8M .. 12M)    kT     (16 MB)   -> later reused as pooled (4 KB)
  //   [12M .. 16M)   v      (16 MB)
  // peak ws = 64 MB
  float* ws = (float*)d_ws;
  float* h      = ws;
  float* q      = ws + 4194304;
  float* kT     = ws + 8388608;       // [b][d][m]
  float* v      = ws + 12582912;
  float* agg    = ws;                 // aliases h (dead after k_qkv)
  float* obn    = ws + 4194304;       // aliases q (dead after k_attn)
  float* pooled = ws + 8388608;       // aliases kT (dead after k_attn)
  float* out = (float*)d_out;

  k_enc<<<16384, 256, 0, stream>>>(lf, enc_w, enc_b, enc_g, enc_be, h);
  k_qkv<<<16384, 256, 0, stream>>>(h, wq, bq, wk, bk, wv, bv, q, kT, v);
  k_attn<<<dim3(256, 8), 256, 0, stream>>>(q, kT, v, coords, mask, gamma, agg);
  k_bn<<<16384, 128, 0, stream>>>(agg, bn_w, bn_b, bn_g, bn_be, obn);
  k_pool<<<8, 128, 0, stream>>>(obn, mask, pooled, out);
  k_head<<<8, 64, 0, stream>>>(pooled, c1w, c1b, c2w, c2b, out);
}

// Round 3
// 1008.720 us; speedup vs baseline: 1.6082x; 1.6082x over previous
//
#include <hip/hip_runtime.h>
#include <hip/hip_bf16.h>

typedef unsigned short ushort_t;
typedef __attribute__((ext_vector_type(8))) short s8;    // 8 bf16 (4 VGPRs)
typedef __attribute__((ext_vector_type(4))) float f4;    // MFMA C/D frag

__device__ __forceinline__ unsigned short f2bf(float f) {
  union { float f; unsigned int u; } c; c.f = f;
  unsigned int r = (c.u + 0x7fffu + ((c.u >> 16) & 1u)) >> 16;
  return (unsigned short)r;
}

// ---------------- encoder: h = relu(LN(x @ enc_w + enc_b)) ----------------
__global__ __launch_bounds__(256) void k_enc(
    const float* __restrict__ x, const float* __restrict__ w,
    const float* __restrict__ bia, const float* __restrict__ g,
    const float* __restrict__ beta, float* __restrict__ h) {
  __shared__ float xs[512];
  __shared__ float red[18];
  const int tid = threadIdx.x;
  const int row = blockIdx.x;
  const float2 u = ((const float2*)(x + (size_t)row * 512))[tid];
  xs[2 * tid] = u.x;
  xs[2 * tid + 1] = u.y;
  __syncthreads();
  const int col = tid;
  float acc = bia[col];
  const float* wc = w + col;
  for (int i = 0; i < 512; i += 8) {
    const float4 xa = *(const float4*)&xs[i];
    const float4 xb = *(const float4*)&xs[i + 4];
    acc += xa.x * wc[(i + 0) * 256] + xa.y * wc[(i + 1) * 256] +
           xa.z * wc[(i + 2) * 256] + xa.w * wc[(i + 3) * 256] +
           xb.x * wc[(i + 4) * 256] + xb.y * wc[(i + 5) * 256] +
           xb.z * wc[(i + 6) * 256] + xb.w * wc[(i + 7) * 256];
  }
  float s1 = acc, s2 = acc * acc;
#pragma unroll
  for (int o = 32; o > 0; o >>= 1) { s1 += __shfl_down(s1, o); s2 += __shfl_down(s2, o); }
  const int wv = tid >> 6;
  if ((tid & 63) == 0) { red[wv] = s1; red[8 + wv] = s2; }
  __syncthreads();
  if (tid == 0) {
    red[16] = red[0] + red[1] + red[2] + red[3];
    red[17] = red[8] + red[9] + red[10] + red[11];
  }
  __syncthreads();
  const float mu = red[16] * (1.f / 256.f);
  const float var = red[17] * (1.f / 256.f) - mu * mu;
  const float rstd = rsqrtf(var + 1e-5f);
  const float hv = (acc - mu) * rstd * g[col] + beta[col];
  h[(size_t)row * 256 + col] = fmaxf(hv, 0.f);
}

// ---------------- qkv: bf16 outputs; q pre-scaled by 1/16 ----------------
__global__ __launch_bounds__(256) void k_qkv(
    const float* __restrict__ h, const float* __restrict__ wq, const float* __restrict__ bq,
    const float* __restrict__ wk, const float* __restrict__ bk,
    const float* __restrict__ wvp, const float* __restrict__ bv,
    ushort_t* __restrict__ q, ushort_t* __restrict__ k, ushort_t* __restrict__ v) {
  __shared__ float hs[256];
  const int tid = threadIdx.x;
  const int row = blockIdx.x;
  hs[tid] = h[(size_t)row * 256 + tid];
  __syncthreads();
  float aq = bq[tid], ak = bk[tid], av = bv[tid];
  for (int i = 0; i < 256; i += 4) {
    const float4 hv = *(const float4*)&hs[i];
    const int o0 = i * 256 + tid;
    aq += hv.x * wq[o0] + hv.y * wq[o0 + 256] + hv.z * wq[o0 + 512] + hv.w * wq[o0 + 768];
    ak += hv.x * wk[o0] + hv.y * wk[o0 + 256] + hv.z * wk[o0 + 512] + hv.w * wk[o0 + 768];
    av += hv.x * wvp[o0] + hv.y * wvp[o0 + 256] + hv.z * wvp[o0 + 512] + hv.w * wvp[o0 + 768];
  }
  q[(size_t)row * 256 + tid] = f2bf(aq * 0.0625f);
  k[(size_t)row * 256 + tid] = f2bf(ak);
  v[(size_t)row * 256 + tid] = f2bf(av);
}

// ---------------- transpose v_bf [b][n][d] -> vt [b][d][n] ----------------
// 2048 blocks x 256 threads; reads coalesced over d, writes 16B chunks
__global__ __launch_bounds__(256) void k_vt(const ushort_t* __restrict__ vbf,
                                            ushort_t* __restrict__ vt) {
  const int bb = blockIdx.x;
  const int b = bb >> 8, rem = bb & 255;
  const int n0 = rem * 8;
  const int d = threadIdx.x;
  __align__(16) ushort_t tmp[8];
#pragma unroll
  for (int j = 0; j < 8; ++j)
    tmp[j] = vbf[((size_t)b * 2048 + n0 + j) * 256 + d];
  *(uint4*)&vt[((size_t)b * 256 + d) * 2048 + n0] = *(const uint4*)tmp;
}

// ---------------- MFMA flash attention (key-split in 2 halves) ----------------
// grid (32 qtiles, 2 ksplit, 8 batch), 256 threads = 4 waves x 16 q-rows
#define KLS 264   // K tile LDS row stride (256 + 8 pad), bf16 elems
#define VTS 72    // VT tile LDS row stride (64 + 8 pad)
#define PLS 72    // P LDS row stride
__global__ __launch_bounds__(256, 2) void k_attn(
    const ushort_t* __restrict__ qb, const ushort_t* __restrict__ kb,
    const ushort_t* __restrict__ vtb,
    const float* __restrict__ coords, const int* __restrict__ mask,
    const float* __restrict__ gam,
    float* __restrict__ Op0, float* __restrict__ Op1,
    float* __restrict__ mws, float* __restrict__ lws) {
  __shared__ short klds[64 * KLS];   // [key][d]    33792 B
  __shared__ short vtl[256 * VTS];   // [d][m]      36864 B
  __shared__ short pl[64 * PLS];     // [row][m]     9216 B
  const int t = threadIdx.x;
  const int wv = t >> 6;
  const int lane = t & 63;
  const int l16 = lane & 15, quad = lane >> 4;
  const int b = blockIdx.z;
  const int ks = blockIdx.y;
  const int qw = blockIdx.x * 64 + wv * 16;   // wave's batch-local q-row base

  // Q A-frags: A[m=l16][k=quad*8+j], 8 chunks of K=32 over D=256
  s8 qa[8];
  {
    const ushort_t* qrow = qb + ((size_t)b * 2048 + qw + l16) * 256;
#pragma unroll
    for (int c = 0; c < 8; ++c)
      qa[c] = *(const s8*)(qrow + c * 32 + quad * 8);
  }
  // row coords for the C-layout rows this lane owns (quad*4 + r)
  float rcx[4], rcy[4];
#pragma unroll
  for (int r = 0; r < 4; ++r) {
    const float2 cc = ((const float2*)coords)[b * 2048 + qw + quad * 4 + r];
    rcx[r] = cc.x; rcy[r] = cc.y;
  }
  const float gamma = fabsf(gam[0]);

  f4 o[16];
#pragma unroll
  for (int i = 0; i < 16; ++i) o[i] = (f4){0.f, 0.f, 0.f, 0.f};
  float mrun[4] = {-1e30f, -1e30f, -1e30f, -1e30f};
  float lrun[4] = {0.f, 0.f, 0.f, 0.f};

  const int kbase = ks * 1024;
  for (int kt = 0; kt < 16; ++kt) {
    const int m0 = kbase + kt * 64;
    __syncthreads();
    // stage K tile (64 keys x 256 d) and VT tile (256 d x 64 m)
    {
      const ushort_t* src = kb + ((size_t)b * 2048 + m0) * 256;
#pragma unroll
      for (int i = 0; i < 8; ++i) {
        const int ch = t + i * 256;
        const int row = ch >> 5, col = ch & 31;
        const uint4 dat = *(const uint4*)(src + row * 256 + col * 8);
        *(uint4*)&klds[row * KLS + col * 8] = dat;
      }
      const ushort_t* vsrc = vtb + (size_t)b * 256 * 2048 + m0;
#pragma unroll
      for (int i = 0; i < 8; ++i) {
        const int ch = t + i * 256;
        const int d = ch >> 3, c8 = ch & 7;
        const uint4 dat = *(const uint4*)(vsrc + (size_t)d * 2048 + c8 * 8);
        *(uint4*)&vtl[d * VTS + c8 * 8] = dat;
      }
    }
    __syncthreads();
    // QK^T: S[16 x 64] per wave (q pre-scaled by 1/16)
    f4 sc[4];
#pragma unroll
    for (int s = 0; s < 4; ++s) sc[s] = (f4){0.f, 0.f, 0.f, 0.f};
#pragma unroll
    for (int s = 0; s < 4; ++s) {
      const short* kr = &klds[(s * 16 + l16) * KLS + quad * 8];
#pragma unroll
      for (int c = 0; c < 8; ++c) {
        const s8 bf = *(const s8*)(kr + c * 32);
        sc[s] = __builtin_amdgcn_mfma_f32_16x16x32_bf16(qa[c], bf, sc[s], 0, 0, 0);
      }
    }
    // online softmax stats (raw scores only; adj/mask applied after)
    float mt[4];
#pragma unroll
    for (int r = 0; r < 4; ++r)
      mt[r] = fmaxf(fmaxf(sc[0][r], sc[1][r]), fmaxf(sc[2][r], sc[3][r]));
#pragma unroll
    for (int o2 = 1; o2 < 16; o2 <<= 1) {
#pragma unroll
      for (int r = 0; r < 4; ++r) mt[r] = fmaxf(mt[r], __shfl_xor(mt[r], o2));
    }
    float alpha[4];
#pragma unroll
    for (int r = 0; r < 4; ++r) {
      const float mn = fmaxf(mrun[r], mt[r]);
      alpha[r] = __expf(mrun[r] - mn);
      mrun[r] = mn;
    }
    float p[4][4], ls[4] = {0.f, 0.f, 0.f, 0.f};
#pragma unroll
    for (int s = 0; s < 4; ++s) {
#pragma unroll
      for (int r = 0; r < 4; ++r) { p[s][r] = __expf(sc[s][r] - mrun[r]); ls[r] += p[s][r]; }
    }
#pragma unroll
    for (int o2 = 1; o2 < 16; o2 <<= 1) {
#pragma unroll
      for (int r = 0; r < 4; ++r) ls[r] += __shfl_xor(ls[r], o2);
    }
#pragma unroll
    for (int r = 0; r < 4; ++r) lrun[r] = lrun[r] * alpha[r] + ls[r];
    // weights = p * exp(-gamma*dist) * maskf -> P in LDS (A-layout roundtrip)
#pragma unroll
    for (int s = 0; s < 4; ++s) {
      const int m = m0 + s * 16 + l16;
      const float2 cc = ((const float2*)coords)[b * 2048 + m];
      const float mf = mask[b * 2048 + m] ? 0.f : 1.f;
#pragma unroll
      for (int r = 0; r < 4; ++r) {
        const float dx = rcx[r] - cc.x, dy = rcy[r] - cc.y;
        const float dist = sqrtf(fmaxf(dx * dx + dy * dy, 0.f));
        const float w = p[s][r] * __expf(-gamma * dist) * mf;
        pl[(wv * 16 + quad * 4 + r) * PLS + s * 16 + l16] = (short)f2bf(w);
      }
    }
    // rescale O by alpha (per C/D row = reg)
#pragma unroll
    for (int i = 0; i < 16; ++i) {
#pragma unroll
      for (int r = 0; r < 4; ++r) o[i][r] *= alpha[r];
    }
    // read P as A-frags (same-wave LDS RAW; lgkmcnt handles)
    const s8 pa0 = *(const s8*)&pl[(wv * 16 + l16) * PLS + quad * 8];
    const s8 pa1 = *(const s8*)&pl[(wv * 16 + l16) * PLS + 32 + quad * 8];
    // PV: O[16 x 256] += P[16 x 64] * V[64 x 256]
#pragma unroll
    for (int ds2 = 0; ds2 < 16; ++ds2) {
      const short* vr = &vtl[(ds2 * 16 + l16) * VTS + quad * 8];
      const s8 b0 = *(const s8*)vr;
      const s8 b1 = *(const s8*)(vr + 32);
      o[ds2] = __builtin_amdgcn_mfma_f32_16x16x32_bf16(pa0, b0, o[ds2], 0, 0, 0);
      o[ds2] = __builtin_amdgcn_mfma_f32_16x16x32_bf16(pa1, b1, o[ds2], 0, 0, 0);
    }
  }
  // write partial O and stats
  float* Op = ks ? Op1 : Op0;
#pragma unroll
  for (int r = 0; r < 4; ++r) {
    float* orow = Op + ((size_t)b * 2048 + qw + quad * 4 + r) * 256 + l16;
#pragma unroll
    for (int ds2 = 0; ds2 < 16; ++ds2) orow[ds2 * 16] = o[ds2][r];
  }
  if (l16 == 0) {
#pragma unroll
    for (int r = 0; r < 4; ++r) {
      mws[ks * 16384 + b * 2048 + qw + quad * 4 + r] = mrun[r];
      lws[ks * 16384 + b * 2048 + qw + quad * 4 + r] = lrun[r];
    }
  }
}

// ---------------- merge the 2 key-split partials (in place over Op0) -------
__global__ __launch_bounds__(256) void k_merge(
    const float* __restrict__ O1, const float* __restrict__ mws,
    const float* __restrict__ lws, float* __restrict__ O0) {
  const int row = blockIdx.x;
  const int d = threadIdx.x;
  const float m0 = mws[row], m1 = mws[16384 + row];
  const float l0 = lws[row], l1 = lws[16384 + row];
  const float M = fmaxf(m0, m1);
  const float a0 = __expf(m0 - M), a1 = __expf(m1 - M);
  const float rd = 1.f / (l0 * a0 + l1 * a1);
  const size_t i = (size_t)row * 256 + d;
  O0[i] = (O0[i] * a0 + O1[i] * a1) * rd;
}

// ---------------- bn: out = relu(LN(agg @ bn_w + bn_b)) ----------------
__global__ __launch_bounds__(128) void k_bn(
    const float* __restrict__ agg, const float* __restrict__ w, const float* __restrict__ bia,
    const float* __restrict__ g, const float* __restrict__ beta, float* __restrict__ out) {
  __shared__ float as_[256];
  __shared__ float red[8];
  const int tid = threadIdx.x;
  const int row = blockIdx.x;
  as_[tid] = agg[(size_t)row * 256 + tid];
  as_[128 + tid] = agg[(size_t)row * 256 + 128 + tid];
  __syncthreads();
  float acc = bia[tid];
  for (int i = 0; i < 256; i += 4) {
    const float4 a4 = *(const float4*)&as_[i];
    const int o0 = i * 128 + tid;
    acc += a4.x * w[o0] + a4.y * w[o0 + 128] + a4.z * w[o0 + 256] + a4.w * w[o0 + 384];
  }
  float s1 = acc, s2 = acc * acc;
#pragma unroll
  for (int o = 32; o > 0; o >>= 1) { s1 += __shfl_down(s1, o); s2 += __shfl_down(s2, o); }
  if ((tid & 63) == 0) { red[tid >> 6] = s1; red[2 + (tid >> 6)] = s2; }
  __syncthreads();
  if (tid == 0) { red[4] = red[0] + red[1]; red[5] = red[2] + red[3]; }
  __syncthreads();
  const float mu = red[4] * (1.f / 128.f);
  const float var = red[5] * (1.f / 128.f) - mu * mu;
  const float rstd = rsqrtf(var + 1e-5f);
  const float ov = (acc - mu) * rstd * g[tid] + beta[tid];
  out[(size_t)row * 128 + tid] = fmaxf(ov, 0.f);
}

// ---------------- masked mean pool, two-stage ----------------
__global__ __launch_bounds__(128) void k_pool1(
    const float* __restrict__ obn, const int* __restrict__ mask,
    float* __restrict__ pp) {
  const int g = blockIdx.x, b = blockIdx.y, d = threadIdx.x;
  const float* ob = obn + ((size_t)b * 2048 + g * 128) * 128;
  const int* mb = mask + b * 2048 + g * 128;
  float s = 0.f, cnt = 0.f;
  for (int n = 0; n < 128; ++n) {
    const float w = mb[n] ? 0.f : 1.f;
    s += w * ob[(size_t)n * 128 + d];
    cnt += w;
  }
  pp[(b * 16 + g) * 132 + d] = s;
  if (d == 0) pp[(b * 16 + g) * 132 + 128] = cnt;
}

__global__ __launch_bounds__(128) void k_pool2(
    const float* __restrict__ pp, float* __restrict__ pooled, float* __restrict__ dout) {
  const int b = blockIdx.x, d = threadIdx.x;
  float s = 0.f, cnt = 0.f;
  for (int g = 0; g < 16; ++g) {
    s += pp[(b * 16 + g) * 132 + d];
    cnt += pp[(b * 16 + g) * 132 + 128];
  }
  const float p = s / fmaxf(cnt, 1e-9f);
  pooled[b * 128 + d] = p;
  dout[80 + b * 128 + d] = p;
}

// ---------------- head ----------------
__global__ __launch_bounds__(64) void k_head(
    const float* __restrict__ pooled, const float* __restrict__ c1w, const float* __restrict__ c1b,
    const float* __restrict__ c2w, const float* __restrict__ c2b, float* __restrict__ dout) {
  __shared__ float ps[128];
  __shared__ float h1[64];
  const int b = blockIdx.x, t = threadIdx.x;
  ps[t] = pooled[b * 128 + t];
  ps[64 + t] = pooled[b * 128 + 64 + t];
  __syncthreads();
  float acc = c1b[t];
  for (int d = 0; d < 128; ++d) acc += ps[d] * c1w[d * 64 + t];
  h1[t] = fmaxf(acc, 0.f);
  __syncthreads();
  if (t < 10) {
    float a2 = c2b[t];
    for (int j = 0; j < 64; ++j) a2 += h1[j] * c2w[j * 10 + t];
    dout[b * 10 + t] = a2;
  }
}

extern "C" void kernel_launch(void* const* d_in, const int* in_sizes, int n_in,
                              void* d_out, int out_size, void* d_ws, size_t ws_size,
                              hipStream_t stream) {
  const float* lf     = (const float*)d_in[0];
  const float* coords = (const float*)d_in[1];
  const int*   mask   = (const int*)d_in[2];
  const float* enc_w  = (const float*)d_in[3];
  const float* enc_b  = (const float*)d_in[4];
  const float* enc_g  = (const float*)d_in[5];
  const float* enc_be = (const float*)d_in[6];
  const float* gamma  = (const float*)d_in[7];
  const float* wq     = (const float*)d_in[8];
  const float* bq     = (const float*)d_in[9];
  const float* wk     = (const float*)d_in[10];
  const float* bk     = (const float*)d_in[11];
  const float* wv     = (const float*)d_in[12];
  const float* bv     = (const float*)d_in[13];
  const float* bn_w   = (const float*)d_in[14];
  const float* bn_b   = (const float*)d_in[15];
  const float* bn_g   = (const float*)d_in[16];
  const float* bn_be  = (const float*)d_in[17];
  const float* c1w    = (const float*)d_in[18];
  const float* c1b    = (const float*)d_in[19];
  const float* c2w    = (const float*)d_in[20];
  const float* c2b    = (const float*)d_in[21];

  // ws layout (float units), 64.3 MB total:
  //  [0,4M)        h  -> Opart0 -> agg (merge in place)
  //  [4M,6M)       q_bf (ushort)  -> obn after attention
  //  [6M,8M)       k_bf (ushort)
  //  [8M,10M)      v_bf (ushort)  -> pooled after k_vt
  //  [10M,12M)     vt_bf (ushort)
  //  [12M,16M)     Opart1
  //  [16M,+32K)    mws   [+32K,+64K) lws   then ppart (8*16*132)
  float* ws = (float*)d_ws;
  float*    h      = ws;
  float*    Op0    = ws;                      // aliases h (dead after k_qkv)
  float*    agg    = ws;                      // merge output in place
  ushort_t* q_bf   = (ushort_t*)(ws + 4194304);
  float*    obn    = ws + 4194304;            // aliases q_bf (dead after attn)
  ushort_t* k_bf   = (ushort_t*)(ws + 6291456);
  ushort_t* v_bf   = (ushort_t*)(ws + 8388608);
  float*    pooled = ws + 8388608;            // aliases v_bf (dead after k_vt)
  ushort_t* vt_bf  = (ushort_t*)(ws + 10485760);
  float*    Op1    = ws + 12582912;
  float*    mws    = ws + 16777216;
  float*    lws    = ws + 16809984;
  float*    ppart  = ws + 16842752;
  float* out = (float*)d_out;

  k_enc<<<16384, 256, 0, stream>>>(lf, enc_w, enc_b, enc_g, enc_be, h);
  k_qkv<<<16384, 256, 0, stream>>>(h, wq, bq, wk, bk, wv, bv, q_bf, k_bf, v_bf);
  k_vt<<<2048, 256, 0, stream>>>(v_bf, vt_bf);
  k_attn<<<dim3(32, 2, 8), 256, 0, stream>>>(q_bf, k_bf, vt_bf, coords, mask, gamma,
                                             Op0, Op1, mws, lws);
  k_merge<<<16384, 256, 0, stream>>>(Op1, mws, lws, Op0);
  k_bn<<<16384, 128, 0, stream>>>(agg, bn_w, bn_b, bn_g, bn_be, obn);
  k_pool1<<<dim3(16, 8), 128, 0, stream>>>(obn, mask, ppart);
  k_pool2<<<8, 128, 0, stream>>>(ppart, pooled, out);
  k_head<<<8, 64, 0, stream>>>(pooled, c1w, c1b, c2w, c2b, out);
}

// Round 4
// 342.952 us; speedup vs baseline: 4.7302x; 2.9413x over previous
//
#include <hip/hip_runtime.h>
#include <hip/hip_bf16.h>

typedef unsigned short ushort_t;
typedef __attribute__((ext_vector_type(8))) short s8;    // 8 bf16 (4 VGPRs)
typedef __attribute__((ext_vector_type(4))) float f4;    // MFMA C/D frag

__device__ __forceinline__ unsigned short f2bf(float f) {
  union { float f; unsigned int u; } c; c.f = f;
  unsigned int r = (c.u + 0x7fffu + ((c.u >> 16) & 1u)) >> 16;
  return (unsigned short)r;
}
__device__ __forceinline__ float bf2f(ushort_t u) {
  union { unsigned int i; float f; } c; c.i = ((unsigned int)u) << 16; return c.f;
}

// ---------------- fp32 -> bf16 bulk convert (n multiple of 4) ----------------
__global__ __launch_bounds__(256) void k_f2b(const float* __restrict__ src,
                                             ushort_t* __restrict__ dst, int n) {
  const int i = (blockIdx.x * 256 + threadIdx.x) * 4;
  if (i < n) {
    const float4 v = *(const float4*)(src + i);
    ushort4 o;
    o.x = f2bf(v.x); o.y = f2bf(v.y); o.z = f2bf(v.z); o.w = f2bf(v.w);
    *(ushort4*)(dst + i) = o;
  }
}

// ------------- transpose + convert: dst[n][k] = bf16(src[k][n]) -------------
__global__ __launch_bounds__(256) void k_wt(const float* __restrict__ src,
                                            ushort_t* __restrict__ dst, int K, int N) {
  const int i = blockIdx.x * 256 + threadIdx.x;
  if (i < K * N) {
    const int n = i / K, k = i - n * K;
    dst[i] = f2bf(src[k * N + n]);
  }
}

// ------- tiled MFMA GEMM + bias + LayerNorm + ReLU, block owns full N -------
// A [M][KK] bf16, WT [NN][KK] bf16 (n-major), out [M][NN] bf16
// grid M/64 blocks, 256 threads = 4 waves; wave tile 32 x NN/2
template <int NN, int KK>
__global__ __launch_bounds__(256, 2) void k_gemm_ln(
    const ushort_t* __restrict__ A, const ushort_t* __restrict__ WT,
    const float* __restrict__ bia, const float* __restrict__ g,
    const float* __restrict__ beta, ushort_t* __restrict__ out) {
  constexpr int NW = NN / 2;    // wave n-width
  constexpr int NF = NW / 16;   // n-frags per wave
  __shared__ short Al[64 * 72];
  __shared__ short Bl[NN * 72];
  __shared__ float red1[64][2], red2[64][2];
  const int t = threadIdx.x;
  const int wv = t >> 6, lane = t & 63, l16 = lane & 15, quad = lane >> 4;
  const int wm = wv >> 1, wn = wv & 1;
  const int row0 = blockIdx.x * 64;

  f4 acc[2][NF];
#pragma unroll
  for (int mf = 0; mf < 2; ++mf)
#pragma unroll
    for (int nf = 0; nf < NF; ++nf) acc[mf][nf] = (f4){0.f, 0.f, 0.f, 0.f};

  for (int k0 = 0; k0 < KK; k0 += 64) {
    __syncthreads();
#pragma unroll
    for (int i = 0; i < 2; ++i) {       // stage A: 64 x 64
      const int ch = t + i * 256;
      const int r = ch >> 3, c8 = ch & 7;
      *(uint4*)&Al[r * 72 + c8 * 8] =
          *(const uint4*)&A[(size_t)(row0 + r) * KK + k0 + c8 * 8];
    }
#pragma unroll
    for (int i = 0; i < NN / 32; ++i) { // stage B: NN x 64
      const int ch = t + i * 256;
      const int r = ch >> 3, c8 = ch & 7;
      *(uint4*)&Bl[r * 72 + c8 * 8] =
          *(const uint4*)&WT[(size_t)r * KK + k0 + c8 * 8];
    }
    __syncthreads();
#pragma unroll
    for (int kc = 0; kc < 2; ++kc) {
      s8 af[2];
      af[0] = *(const s8*)&Al[(wm * 32 + l16) * 72 + kc * 32 + quad * 8];
      af[1] = *(const s8*)&Al[(wm * 32 + 16 + l16) * 72 + kc * 32 + quad * 8];
#pragma unroll
      for (int nf = 0; nf < NF; ++nf) {
        const s8 bf = *(const s8*)&Bl[(wn * NW + nf * 16 + l16) * 72 + kc * 32 + quad * 8];
        acc[0][nf] = __builtin_amdgcn_mfma_f32_16x16x32_bf16(af[0], bf, acc[0][nf], 0, 0, 0);
        acc[1][nf] = __builtin_amdgcn_mfma_f32_16x16x32_bf16(af[1], bf, acc[1][nf], 0, 0, 0);
      }
    }
  }
  // epilogue: bias, LN over NN, ReLU
  float bi[NF], gg[NF], bb[NF];
#pragma unroll
  for (int nf = 0; nf < NF; ++nf) {
    const int col = wn * NW + nf * 16 + l16;
    bi[nf] = bia[col]; gg[nf] = g[col]; bb[nf] = beta[col];
  }
  float s1[2][4], s2[2][4];
#pragma unroll
  for (int mf = 0; mf < 2; ++mf)
#pragma unroll
    for (int r = 0; r < 4; ++r) { s1[mf][r] = 0.f; s2[mf][r] = 0.f; }
#pragma unroll
  for (int mf = 0; mf < 2; ++mf)
#pragma unroll
    for (int nf = 0; nf < NF; ++nf)
#pragma unroll
      for (int r = 0; r < 4; ++r) {
        const float v = acc[mf][nf][r] + bi[nf];
        acc[mf][nf][r] = v;
        s1[mf][r] += v; s2[mf][r] += v * v;
      }
#pragma unroll
  for (int m = 1; m < 16; m <<= 1) {
#pragma unroll
    for (int mf = 0; mf < 2; ++mf)
#pragma unroll
      for (int r = 0; r < 4; ++r) {
        s1[mf][r] += __shfl_xor(s1[mf][r], m);
        s2[mf][r] += __shfl_xor(s2[mf][r], m);
      }
  }
  if (l16 == 0) {
#pragma unroll
    for (int mf = 0; mf < 2; ++mf)
#pragma unroll
      for (int r = 0; r < 4; ++r) {
        const int rl = wm * 32 + mf * 16 + quad * 4 + r;
        red1[rl][wn] = s1[mf][r]; red2[rl][wn] = s2[mf][r];
      }
  }
  __syncthreads();
#pragma unroll
  for (int mf = 0; mf < 2; ++mf)
#pragma unroll
    for (int r = 0; r < 4; ++r) {
      const int rl = wm * 32 + mf * 16 + quad * 4 + r;
      const float mu = (red1[rl][0] + red1[rl][1]) * (1.f / NN);
      const float var = (red2[rl][0] + red2[rl][1]) * (1.f / NN) - mu * mu;
      const float rstd = rsqrtf(var + 1e-5f);
#pragma unroll
      for (int nf = 0; nf < NF; ++nf) {
        const int col = wn * NW + nf * 16 + l16;
        const float v = (acc[mf][nf][r] - mu) * rstd * gg[nf] + bb[nf];
        out[(size_t)(row0 + rl) * NN + col] = f2bf(fmaxf(v, 0.f));
      }
    }
}

// ---- QKV GEMM: A=h_bf [16384][256], WT=wqkvT [768][256]; q scaled 1/16 ----
// grid (256, 6): 64-row x 128-col tiles; v-tiles write VT directly
__global__ __launch_bounds__(256, 4) void k_gemm_qkv(
    const ushort_t* __restrict__ A, const ushort_t* __restrict__ WT,
    const float* __restrict__ bq, const float* __restrict__ bk,
    const float* __restrict__ bv,
    ushort_t* __restrict__ q, ushort_t* __restrict__ k, ushort_t* __restrict__ vt) {
  __shared__ short Al[64 * 72];
  __shared__ short Bl[128 * 72];
  const int t = threadIdx.x;
  const int wv = t >> 6, lane = t & 63, l16 = lane & 15, quad = lane >> 4;
  const int wm = wv >> 1, wn = wv & 1;
  const int row0 = blockIdx.x * 64;
  const int nb = blockIdx.y;           // 0..5
  const int type = nb >> 1;            // 0:q 1:k 2:v
  const ushort_t* wtb = WT + (size_t)nb * 128 * 256;

  f4 acc[2][4];
#pragma unroll
  for (int mf = 0; mf < 2; ++mf)
#pragma unroll
    for (int nf = 0; nf < 4; ++nf) acc[mf][nf] = (f4){0.f, 0.f, 0.f, 0.f};

  for (int k0 = 0; k0 < 256; k0 += 64) {
    __syncthreads();
#pragma unroll
    for (int i = 0; i < 2; ++i) {
      const int ch = t + i * 256;
      const int r = ch >> 3, c8 = ch & 7;
      *(uint4*)&Al[r * 72 + c8 * 8] =
          *(const uint4*)&A[(size_t)(row0 + r) * 256 + k0 + c8 * 8];
    }
#pragma unroll
    for (int i = 0; i < 4; ++i) {
      const int ch = t + i * 256;
      const int r = ch >> 3, c8 = ch & 7;
      *(uint4*)&Bl[r * 72 + c8 * 8] =
          *(const uint4*)&wtb[(size_t)r * 256 + k0 + c8 * 8];
    }
    __syncthreads();
#pragma unroll
    for (int kc = 0; kc < 2; ++kc) {
      s8 af[2];
      af[0] = *(const s8*)&Al[(wm * 32 + l16) * 72 + kc * 32 + quad * 8];
      af[1] = *(const s8*)&Al[(wm * 32 + 16 + l16) * 72 + kc * 32 + quad * 8];
#pragma unroll
      for (int nf = 0; nf < 4; ++nf) {
        const s8 bf = *(const s8*)&Bl[(wn * 64 + nf * 16 + l16) * 72 + kc * 32 + quad * 8];
        acc[0][nf] = __builtin_amdgcn_mfma_f32_16x16x32_bf16(af[0], bf, acc[0][nf], 0, 0, 0);
        acc[1][nf] = __builtin_amdgcn_mfma_f32_16x16x32_bf16(af[1], bf, acc[1][nf], 0, 0, 0);
      }
    }
  }
  const float* bias = (type == 0) ? bq : (type == 1) ? bk : bv;
#pragma unroll
  for (int nf = 0; nf < 4; ++nf) {
    const int colg = nb * 128 + wn * 64 + nf * 16 + l16;   // 0..767
    const int col = colg - type * 256;                     // 0..255 within matrix
    const float bi = bias[col];
    if (type == 2) {
      // v: write VT[b][col][n], 4 consecutive tokens packed
      const int b = row0 >> 11;
#pragma unroll
      for (int mf = 0; mf < 2; ++mf) {
        const int n = (row0 & 2047) + wm * 32 + mf * 16 + quad * 4;
        ushort4 pk;
        pk.x = f2bf(acc[mf][nf][0] + bi);
        pk.y = f2bf(acc[mf][nf][1] + bi);
        pk.z = f2bf(acc[mf][nf][2] + bi);
        pk.w = f2bf(acc[mf][nf][3] + bi);
        *(ushort4*)&vt[((size_t)b * 256 + col) * 2048 + n] = pk;
      }
    } else {
      ushort_t* dst = (type == 0) ? q : k;
      const float sc = (type == 0) ? 0.0625f : 1.f;
#pragma unroll
      for (int mf = 0; mf < 2; ++mf)
#pragma unroll
        for (int r = 0; r < 4; ++r) {
          const int row = row0 + wm * 32 + mf * 16 + quad * 4 + r;
          dst[(size_t)row * 256 + col] = f2bf((acc[mf][nf][r] + bi) * sc);
        }
    }
  }
}

// ---------------- MFMA flash attention (key-split in 2 halves) ----------------
#define KLS 264
#define VTS 72
#define PLS 72
__global__ __launch_bounds__(256, 2) void k_attn(
    const ushort_t* __restrict__ qb, const ushort_t* __restrict__ kb,
    const ushort_t* __restrict__ vtb,
    const float* __restrict__ coords, const int* __restrict__ mask,
    const float* __restrict__ gam,
    float* __restrict__ Op0, float* __restrict__ Op1,
    float* __restrict__ mws, float* __restrict__ lws) {
  __shared__ short klds[64 * KLS];
  __shared__ short vtl[256 * VTS];
  __shared__ short pl[64 * PLS];
  const int t = threadIdx.x;
  const int wv = t >> 6;
  const int lane = t & 63;
  const int l16 = lane & 15, quad = lane >> 4;
  const int b = blockIdx.z;
  const int ks = blockIdx.y;
  const int qw = blockIdx.x * 64 + wv * 16;

  s8 qa[8];
  {
    const ushort_t* qrow = qb + ((size_t)b * 2048 + qw + l16) * 256;
#pragma unroll
    for (int c = 0; c < 8; ++c)
      qa[c] = *(const s8*)(qrow + c * 32 + quad * 8);
  }
  float rcx[4], rcy[4];
#pragma unroll
  for (int r = 0; r < 4; ++r) {
    const float2 cc = ((const float2*)coords)[b * 2048 + qw + quad * 4 + r];
    rcx[r] = cc.x; rcy[r] = cc.y;
  }
  const float gamma = fabsf(gam[0]);

  f4 o[16];
#pragma unroll
  for (int i = 0; i < 16; ++i) o[i] = (f4){0.f, 0.f, 0.f, 0.f};
  float mrun[4] = {-1e30f, -1e30f, -1e30f, -1e30f};
  float lrun[4] = {0.f, 0.f, 0.f, 0.f};

  const int kbase = ks * 1024;
  for (int kt = 0; kt < 16; ++kt) {
    const int m0 = kbase + kt * 64;
    __syncthreads();
    {
      const ushort_t* src = kb + ((size_t)b * 2048 + m0) * 256;
#pragma unroll
      for (int i = 0; i < 8; ++i) {
        const int ch = t + i * 256;
        const int row = ch >> 5, col = ch & 31;
        const uint4 dat = *(const uint4*)(src + row * 256 + col * 8);
        *(uint4*)&klds[row * KLS + col * 8] = dat;
      }
      const ushort_t* vsrc = vtb + (size_t)b * 256 * 2048 + m0;
#pragma unroll
      for (int i = 0; i < 8; ++i) {
        const int ch = t + i * 256;
        const int d = ch >> 3, c8 = ch & 7;
        const uint4 dat = *(const uint4*)(vsrc + (size_t)d * 2048 + c8 * 8);
        *(uint4*)&vtl[d * VTS + c8 * 8] = dat;
      }
    }
    __syncthreads();
    f4 sc[4];
#pragma unroll
    for (int s = 0; s < 4; ++s) sc[s] = (f4){0.f, 0.f, 0.f, 0.f};
#pragma unroll
    for (int s = 0; s < 4; ++s) {
      const short* kr = &klds[(s * 16 + l16) * KLS + quad * 8];
#pragma unroll
      for (int c = 0; c < 8; ++c) {
        const s8 bf = *(const s8*)(kr + c * 32);
        sc[s] = __builtin_amdgcn_mfma_f32_16x16x32_bf16(qa[c], bf, sc[s], 0, 0, 0);
      }
    }
    float mt[4];
#pragma unroll
    for (int r = 0; r < 4; ++r)
      mt[r] = fmaxf(fmaxf(sc[0][r], sc[1][r]), fmaxf(sc[2][r], sc[3][r]));
#pragma unroll
    for (int o2 = 1; o2 < 16; o2 <<= 1) {
#pragma unroll
      for (int r = 0; r < 4; ++r) mt[r] = fmaxf(mt[r], __shfl_xor(mt[r], o2));
    }
    float alpha[4];
#pragma unroll
    for (int r = 0; r < 4; ++r) {
      const float mn = fmaxf(mrun[r], mt[r]);
      alpha[r] = __expf(mrun[r] - mn);
      mrun[r] = mn;
    }
    float p[4][4], ls[4] = {0.f, 0.f, 0.f, 0.f};
#pragma unroll
    for (int s = 0; s < 4; ++s) {
#pragma unroll
      for (int r = 0; r < 4; ++r) { p[s][r] = __expf(sc[s][r] - mrun[r]); ls[r] += p[s][r]; }
    }
#pragma unroll
    for (int o2 = 1; o2 < 16; o2 <<= 1) {
#pragma unroll
      for (int r = 0; r < 4; ++r) ls[r] += __shfl_xor(ls[r], o2);
    }
#pragma unroll
    for (int r = 0; r < 4; ++r) lrun[r] = lrun[r] * alpha[r] + ls[r];
#pragma unroll
    for (int s = 0; s < 4; ++s) {
      const int m = m0 + s * 16 + l16;
      const float2 cc = ((const float2*)coords)[b * 2048 + m];
      const float mf = mask[b * 2048 + m] ? 0.f : 1.f;
#pragma unroll
      for (int r = 0; r < 4; ++r) {
        const float dx = rcx[r] - cc.x, dy = rcy[r] - cc.y;
        const float dist = sqrtf(fmaxf(dx * dx + dy * dy, 0.f));
        const float w = p[s][r] * __expf(-gamma * dist) * mf;
        pl[(wv * 16 + quad * 4 + r) * PLS + s * 16 + l16] = (short)f2bf(w);
      }
    }
#pragma unroll
    for (int i = 0; i < 16; ++i) {
#pragma unroll
      for (int r = 0; r < 4; ++r) o[i][r] *= alpha[r];
    }
    const s8 pa0 = *(const s8*)&pl[(wv * 16 + l16) * PLS + quad * 8];
    const s8 pa1 = *(const s8*)&pl[(wv * 16 + l16) * PLS + 32 + quad * 8];
#pragma unroll
    for (int ds2 = 0; ds2 < 16; ++ds2) {
      const short* vr = &vtl[(ds2 * 16 + l16) * VTS + quad * 8];
      const s8 b0 = *(const s8*)vr;
      const s8 b1 = *(const s8*)(vr + 32);
      o[ds2] = __builtin_amdgcn_mfma_f32_16x16x32_bf16(pa0, b0, o[ds2], 0, 0, 0);
      o[ds2] = __builtin_amdgcn_mfma_f32_16x16x32_bf16(pa1, b1, o[ds2], 0, 0, 0);
    }
  }
  float* Op = ks ? Op1 : Op0;
#pragma unroll
  for (int r = 0; r < 4; ++r) {
    float* orow = Op + ((size_t)b * 2048 + qw + quad * 4 + r) * 256 + l16;
#pragma unroll
    for (int ds2 = 0; ds2 < 16; ++ds2) orow[ds2 * 16] = o[ds2][r];
  }
  if (l16 == 0) {
#pragma unroll
    for (int r = 0; r < 4; ++r) {
      mws[ks * 16384 + b * 2048 + qw + quad * 4 + r] = mrun[r];
      lws[ks * 16384 + b * 2048 + qw + quad * 4 + r] = lrun[r];
    }
  }
}

// ------- merge 2 key-split partials -> agg bf16 -------
__global__ __launch_bounds__(256) void k_merge(
    const float* __restrict__ O0, const float* __restrict__ O1,
    const float* __restrict__ mws, const float* __restrict__ lws,
    ushort_t* __restrict__ aggb) {
  const int row = blockIdx.x;
  const int d = threadIdx.x;
  const float m0 = mws[row], m1 = mws[16384 + row];
  const float l0 = lws[row], l1 = lws[16384 + row];
  const float M = fmaxf(m0, m1);
  const float a0 = __expf(m0 - M), a1 = __expf(m1 - M);
  const float rd = 1.f / (l0 * a0 + l1 * a1);
  const size_t i = (size_t)row * 256 + d;
  aggb[i] = f2bf((O0[i] * a0 + O1[i] * a1) * rd);
}

// ---------------- masked mean pool, two-stage (obn in bf16) ----------------
__global__ __launch_bounds__(128) void k_pool1(
    const ushort_t* __restrict__ obn, const int* __restrict__ mask,
    float* __restrict__ pp) {
  const int g = blockIdx.x, b = blockIdx.y, d = threadIdx.x;
  const ushort_t* ob = obn + ((size_t)b * 2048 + g * 128) * 128;
  const int* mb = mask + b * 2048 + g * 128;
  float s = 0.f, cnt = 0.f;
  for (int n = 0; n < 128; ++n) {
    const float w = mb[n] ? 0.f : 1.f;
    s += w * bf2f(ob[(size_t)n * 128 + d]);
    cnt += w;
  }
  pp[(b * 16 + g) * 132 + d] = s;
  if (d == 0) pp[(b * 16 + g) * 132 + 128] = cnt;
}

__global__ __launch_bounds__(128) void k_pool2(
    const float* __restrict__ pp, float* __restrict__ pooled, float* __restrict__ dout) {
  const int b = blockIdx.x, d = threadIdx.x;
  float s = 0.f, cnt = 0.f;
  for (int g = 0; g < 16; ++g) {
    s += pp[(b * 16 + g) * 132 + d];
    cnt += pp[(b * 16 + g) * 132 + 128];
  }
  const float p = s / fmaxf(cnt, 1e-9f);
  pooled[b * 128 + d] = p;
  dout[80 + b * 128 + d] = p;
}

// ---------------- head ----------------
__global__ __launch_bounds__(64) void k_head(
    const float* __restrict__ pooled, const float* __restrict__ c1w, const float* __restrict__ c1b,
    const float* __restrict__ c2w, const float* __restrict__ c2b, float* __restrict__ dout) {
  __shared__ float ps[128];
  __shared__ float h1[64];
  const int b = blockIdx.x, t = threadIdx.x;
  ps[t] = pooled[b * 128 + t];
  ps[64 + t] = pooled[b * 128 + 64 + t];
  __syncthreads();
  float acc = c1b[t];
  for (int d = 0; d < 128; ++d) acc += ps[d] * c1w[d * 64 + t];
  h1[t] = fmaxf(acc, 0.f);
  __syncthreads();
  if (t < 10) {
    float a2 = c2b[t];
    for (int j = 0; j < 64; ++j) a2 += h1[j] * c2w[j * 10 + t];
    dout[b * 10 + t] = a2;
  }
}

extern "C" void kernel_launch(void* const* d_in, const int* in_sizes, int n_in,
                              void* d_out, int out_size, void* d_ws, size_t ws_size,
                              hipStream_t stream) {
  const float* lf     = (const float*)d_in[0];
  const float* coords = (const float*)d_in[1];
  const int*   mask   = (const int*)d_in[2];
  const float* enc_w  = (const float*)d_in[3];
  const float* enc_b  = (const float*)d_in[4];
  const float* enc_g  = (const float*)d_in[5];
  const float* enc_be = (const float*)d_in[6];
  const float* gamma  = (const float*)d_in[7];
  const float* wq     = (const float*)d_in[8];
  const float* bq     = (const float*)d_in[9];
  const float* wk     = (const float*)d_in[10];
  const float* bk     = (const float*)d_in[11];
  const float* wv     = (const float*)d_in[12];
  const float* bv     = (const float*)d_in[13];
  const float* bn_w   = (const float*)d_in[14];
  const float* bn_b   = (const float*)d_in[15];
  const float* bn_g   = (const float*)d_in[16];
  const float* bn_be  = (const float*)d_in[17];
  const float* c1w    = (const float*)d_in[18];
  const float* c1b    = (const float*)d_in[19];
  const float* c2w    = (const float*)d_in[20];
  const float* c2b    = (const float*)d_in[21];

  // ws layout (float units), ~68.2 MB:
  //  [0,       4194304)  lf_bf (8.4M us)  -> Op0 fp32 (attn partial)
  //  [4194304, 6291456)  h_bf             -> agg_bf (merge out)
  //  [6291456, 8388608)  q_bf             -> obn_bf
  //  [8388608,10485760)  k_bf
  //  [10485760,12582912) vt_bf
  //  [12582912,16777216) Op1 fp32
  //  [16777216,...)      enc_wT | wqkvT | bn_wT | mws | lws | ppart | pooled
  float* ws = (float*)d_ws;
  ushort_t* lf_bf  = (ushort_t*)ws;
  float*    Op0    = ws;
  ushort_t* h_bf   = (ushort_t*)(ws + 4194304);
  ushort_t* agg_bf = (ushort_t*)(ws + 4194304);
  ushort_t* q_bf   = (ushort_t*)(ws + 6291456);
  ushort_t* obn_bf = (ushort_t*)(ws + 6291456);
  ushort_t* k_bf   = (ushort_t*)(ws + 8388608);
  ushort_t* vt_bf  = (ushort_t*)(ws + 10485760);
  float*    Op1    = ws + 12582912;
  ushort_t* enc_wT = (ushort_t*)(ws + 16777216);   // [256][512]
  ushort_t* wqkvT  = (ushort_t*)(ws + 16842752);   // [768][256]
  ushort_t* bn_wT  = (ushort_t*)(ws + 16941056);   // [128][256]
  float*    mws    = ws + 16957440;
  float*    lws    = ws + 16990208;
  float*    ppart  = ws + 17022976;
  float*    pooled = ws + 17039872;
  float* out = (float*)d_out;

  // prolog: convert/transpose
  k_f2b<<<8192, 256, 0, stream>>>(lf, lf_bf, 8388608);
  k_wt<<<512, 256, 0, stream>>>(enc_w, enc_wT, 512, 256);
  k_wt<<<256, 256, 0, stream>>>(wq, wqkvT, 256, 256);
  k_wt<<<256, 256, 0, stream>>>(wk, wqkvT + 65536, 256, 256);
  k_wt<<<256, 256, 0, stream>>>(wv, wqkvT + 131072, 256, 256);
  k_wt<<<128, 256, 0, stream>>>(bn_w, bn_wT, 256, 128);

  k_gemm_ln<256, 512><<<256, 256, 0, stream>>>(lf_bf, enc_wT, enc_b, enc_g, enc_be, h_bf);
  k_gemm_qkv<<<dim3(256, 6), 256, 0, stream>>>(h_bf, wqkvT, bq, bk, bv, q_bf, k_bf, vt_bf);
  k_attn<<<dim3(32, 2, 8), 256, 0, stream>>>(q_bf, k_bf, vt_bf, coords, mask, gamma,
                                             Op0, Op1, mws, lws);
  k_merge<<<16384, 256, 0, stream>>>(Op0, Op1, mws, lws, agg_bf);
  k_gemm_ln<128, 256><<<256, 256, 0, stream>>>(agg_bf, bn_wT, bn_b, bn_g, bn_be, obn_bf);
  k_pool1<<<dim3(16, 8), 128, 0, stream>>>(obn_bf, mask, ppart);
  k_pool2<<<8, 128, 0, stream>>>(ppart, pooled, out);
  k_head<<<8, 64, 0, stream>>>(pooled, c1w, c1b, c2w, c2b, out);
}